// Round 4
// baseline (309.730 us; speedup 1.0000x reference)
//
#include <hip/hip_runtime.h>
#include <hip/hip_fp16.h>

// GNN mean-aggregate + dual GEMM. N=50000, E=1.6M, DIM=128, fp32 in/out.
// Pipeline: fixed-capacity bucket bin (block-local LDS counting sort +
// coalesced streaming writeback) -> per-bucket counting sort (8-way
// privatized) -> column-tiled register gather -> MFMA f16 GEMM in-place.
// R1: 4-deep pipeline (NEUTRAL - not latency-bound).
// R2: full-width 1-wave/node gather: VALU 48->21% but FETCH 75->284MB.
// R3: tile loop inside wave: FETCH 445MB (waves de-phase across tiles,
//     concurrent footprint > L2) - REVERTED. L2 residency comes from
//     dispatch-ordered tile passes (grid.y=tile), keep that.
// R4: tile passes (R0 dispatch) + treeless gather: 16 nodes/wave, each
//     4-lane group streams its node's entries, lane owns one uint4 of
//     the 64B row-tile, 4 depth-slot accumulators. No shfl tree; the
//     per-(node,tile) overhead (R0's ~42us VALU) collapses to a 2-level
//     in-register merge + 1 store.

constexpr int DIM    = 128;
constexpr int NBMAX  = 512;    // coarse buckets (node>>7); N=50000 -> 391
constexpr int EPB    = 2048;   // edges per binning block (256 thr x 8)
constexpr int CAP    = 9216;   // entries per bucket (E[cnt]=8184, ~11 sigma)
constexpr int COLT   = 32;     // columns per tile -> 4 tiles
constexpr int NTILES = DIM / COLT;

typedef _Float16 half8 __attribute__((ext_vector_type(8)));
typedef __attribute__((ext_vector_type(4))) float f32x4;

__device__ __forceinline__ unsigned hadd2u(unsigned a, unsigned b) {
    __half2 ha = *reinterpret_cast<__half2*>(&a);
    __half2 hb = *reinterpret_cast<__half2*>(&b);
    __half2 r  = __hadd2(ha, hb);
    return *reinterpret_cast<unsigned*>(&r);
}
__device__ __forceinline__ unsigned hmul2u(unsigned a, __half2 s) {
    __half2 ha = *reinterpret_cast<__half2*>(&a);
    __half2 r  = __hmul2(ha, s);
    return *reinterpret_cast<unsigned*>(&r);
}
__device__ __forceinline__ unsigned packf16(float x, float y) {
    __half2 h = __floats2half2_rn(x, y);
    return *reinterpret_cast<unsigned*>(&h);
}
__device__ __forceinline__ uint4 hadd2q(uint4 a, uint4 b) {
    uint4 r;
    r.x = hadd2u(a.x, b.x);
    r.y = hadd2u(a.y, b.y);
    r.z = hadd2u(a.z, b.z);
    r.w = hadd2u(a.w, b.w);
    return r;
}

// --- K0: pack [Wn;Ws] -> Bp f16 (B-fragment order) AND init bucket cursors ---
__global__ __launch_bounds__(256) void k_packw_init(
    const float* __restrict__ Wn, const float* __restrict__ Ws,
    unsigned short* __restrict__ Bp, int* __restrict__ bucket_cur, int nb)
{
    int i = blockIdx.x * 256 + threadIdx.x;
    if (i < nb) bucket_cur[i] = i * CAP;
    if (i >= 8 * 128 * 4 * 8) return;
    int j    = i & 7;
    int quad = (i >> 3) & 3;
    int n    = (i >> 5) & 127;
    int kb   = i >> 12;
    int k = kb * 32 + quad * 8 + j;
    float v = (k < 128) ? Wn[k * 128 + n] : Ws[(k - 128) * 128 + n];
    __half h = __float2half_rn(v);
    Bp[i] = *reinterpret_cast<unsigned short*>(&h);
}

// --- K1: bin endpoints into fixed-cap buckets.
// Per-wave LDS histogram -> global frontier alloc (1 atomic-return per
// (block,bucket)) -> block-local LDS counting sort -> coalesced writeback. ---
__global__ __launch_bounds__(256) void k_bin(
    const int* __restrict__ edge, int* __restrict__ bucket_cur,
    unsigned* __restrict__ entries, int n_edges, int nb)
{
    __shared__ int lh[4][NBMAX];
    __shared__ int Lb[NBMAX];
    __shared__ int gb[NBMAX];
    __shared__ int sc[512];
    __shared__ unsigned sorted[2 * EPB];
    __shared__ int      gaddr[2 * EPB];

    int t = threadIdx.x;
    int w = t >> 6;
    for (int i = t; i < 4 * NBMAX; i += 256) ((int*)lh)[i] = 0;
    __syncthreads();

    int e0 = blockIdx.x * EPB;
    int2 ev[8];
    #pragma unroll
    for (int k = 0; k < 8; k++) {
        int idx = e0 + k * 256 + t;
        if (idx < n_edges) {
            ev[k] = ((const int2*)edge)[idx];
            atomicAdd(&lh[w][ev[k].x >> 7], 1);
            atomicAdd(&lh[w][ev[k].y >> 7], 1);
        } else {
            ev[k].x = -1;
        }
    }
    __syncthreads();

    for (int i = t; i < 512; i += 256)
        sc[i] = (i < nb) ? (lh[0][i] + lh[1][i] + lh[2][i] + lh[3][i]) : 0;
    __syncthreads();
    for (int d = 1; d < 512; d <<= 1) {
        int v0 = 0, v1 = 0;
        int i0 = t, i1 = t + 256;
        if (i0 >= d) v0 = sc[i0 - d];
        if (i1 >= d) v1 = sc[i1 - d];
        __syncthreads();
        if (i0 >= d) sc[i0] += v0;
        if (i1 >= d) sc[i1] += v1;
        __syncthreads();
    }
    for (int i = t; i < nb; i += 256) {
        int c0 = lh[0][i], c1 = lh[1][i], c2 = lh[2][i], c3 = lh[3][i];
        int tot = c0 + c1 + c2 + c3;
        int L = sc[i] - tot;
        Lb[i] = L;
        gb[i] = tot ? atomicAdd(&bucket_cur[i], tot) : 0;
        lh[0][i] = L;
        lh[1][i] = L + c0;
        lh[2][i] = L + c0 + c1;
        lh[3][i] = L + c0 + c1 + c2;
    }
    __syncthreads();

    #pragma unroll
    for (int k = 0; k < 8; k++) {
        int a = ev[k].x;
        if (a < 0) continue;
        int b = ev[k].y;
        int ba = a >> 7, bb = b >> 7;
        int sa = atomicAdd(&lh[w][ba], 1);
        sorted[sa] = ((unsigned)(a & 127) << 16) | (unsigned)b;
        gaddr[sa]  = gb[ba] + sa - Lb[ba];
        int sb = atomicAdd(&lh[w][bb], 1);
        sorted[sb] = ((unsigned)(b & 127) << 16) | (unsigned)a;
        gaddr[sb]  = gb[bb] + sb - Lb[bb];
    }
    __syncthreads();

    int cntb = sc[511];
    for (int p = t; p < cntb; p += 256)
        entries[gaddr[p]] = sorted[p];
}

// --- K2: per-bucket counting sort, 512 threads, 8-way privatized cursors ---
__global__ __launch_bounds__(512) void k_csort(
    const unsigned* __restrict__ entries, const int* __restrict__ bucket_cur,
    unsigned* __restrict__ offsets, int* __restrict__ degs,
    unsigned short* __restrict__ nbr, int n_nodes)
{
    int b    = blockIdx.x;
    int base = b * CAP;
    int cnt  = bucket_cur[b] - base;
    __shared__ int lh[8][128];
    __shared__ int scn[128];
    int t = threadIdx.x;
    int w = t >> 6;
    for (int i = t; i < 8 * 128; i += 512) ((int*)lh)[i] = 0;
    __syncthreads();
    for (int i = t; i < cnt; i += 512)
        atomicAdd(&lh[w][entries[base + i] >> 16], 1);
    __syncthreads();
    int tot = 0;
    if (t < 128) {
        #pragma unroll
        for (int ww = 0; ww < 8; ww++) tot += lh[ww][t];
        scn[t] = tot;
    }
    __syncthreads();
    for (int d = 1; d < 128; d <<= 1) {
        int u = (t >= d && t < 128) ? scn[t - d] : 0;
        __syncthreads();
        if (t >= d && t < 128) scn[t] += u;
        __syncthreads();
    }
    if (t < 128) {
        int excl = scn[t] - tot;
        int node = (b << 7) + t;
        if (node < n_nodes) {
            offsets[node] = (unsigned)(base + excl);
            degs[node]    = tot;
        }
        int run = excl;
        #pragma unroll
        for (int ww = 0; ww < 8; ww++) { int c = lh[ww][t]; lh[ww][t] = run; run += c; }
    }
    __syncthreads();
    for (int i = t; i < cnt; i += 512) {
        unsigned e = entries[base + i];
        int slot = atomicAdd(&lh[w][e >> 16], 1);
        nbr[base + slot] = (unsigned short)(e & 0xFFFFu);
    }
}

// --- K3: x fp32 -> xt (4 f16 column tiles) AND x-half of f16 A (cols 128..255) ---
__global__ __launch_bounds__(256) void k_tof16t(
    const float* __restrict__ x, unsigned* __restrict__ xt,
    unsigned* __restrict__ abf, int n_nodes)
{
    int i = blockIdx.x * 256 + threadIdx.x;
    int per = n_nodes * 16;
    if (i >= per * NTILES) return;
    int t   = i / per;
    int rem = i - t * per;
    int n   = rem >> 4;
    int u   = rem & 15;
    float2 f = ((const float2*)(x + (size_t)n * DIM + t * COLT))[u];
    unsigned pk = packf16(f.x, f.y);
    xt[i] = pk;
    abf[(size_t)n * 128 + 64 + t * 16 + u] = pk;
}

// --- K4 (R4): treeless tiled gather + mean. grid.y = tile (dispatch-
// ordered passes keep the 3.2MB tile L2-resident). 16 nodes/wave: 4-lane
// group per node, lane owns one uint4 (16B) of the 64B row-tile and
// streams the node's entries with 4 depth-slot accumulators (8 loads in
// flight). Groups diverge on trip count via exec mask (no predication
// instructions). Epilogue: 2-level in-register merge + scale + 16B store.
__global__ __launch_bounds__(256) void k_gather(
    const unsigned* __restrict__ xt,        // [NTILES][n_nodes][16] uints
    const unsigned* __restrict__ offsets,
    const int* __restrict__ degs,
    const unsigned short* __restrict__ nbr,
    unsigned* __restrict__ abf, int n_nodes)
{
    int wave = threadIdx.x >> 6;
    int lane = threadIdx.x & 63;
    int grp  = lane >> 2;          // 0..15: node within the wave
    int u    = lane & 3;           // uint4 within the 64B row-tile
    int node = blockIdx.x * 64 + wave * 16 + grp;
    int tile = blockIdx.y;
    const uint4* xt_tile = (const uint4*)(xt + (size_t)tile * n_nodes * 16);
    bool valid = node < n_nodes;
    int base = 0, deg = 0;
    if (valid) { base = (int)offsets[node]; deg = degs[node]; }
    int end = base + deg;

    uint4 s0 = {0u, 0u, 0u, 0u};
    uint4 s1 = s0, s2 = s0, s3 = s0;

    int i = base;
    for (; i + 3 < end; i += 4) {
        int v0 = nbr[i];
        int v1 = nbr[i + 1];
        int v2 = nbr[i + 2];
        int v3 = nbr[i + 3];
        uint4 w0 = xt_tile[v0 * 4 + u];
        uint4 w1 = xt_tile[v1 * 4 + u];
        uint4 w2 = xt_tile[v2 * 4 + u];
        uint4 w3 = xt_tile[v3 * 4 + u];
        s0 = hadd2q(s0, w0);
        s1 = hadd2q(s1, w1);
        s2 = hadd2q(s2, w2);
        s3 = hadd2q(s3, w3);
    }
    for (; i < end; i++) {
        int v = nbr[i];
        s0 = hadd2q(s0, xt_tile[v * 4 + u]);
    }

    uint4 m = hadd2q(hadd2q(s0, s1), hadd2q(s2, s3));

    if (valid) {
        float inv = 1.0f / fmaxf((float)deg, 1.0f);
        __half2 iv = __float2half2_rn(inv);
        uint4 o;
        o.x = hmul2u(m.x, iv);
        o.y = hmul2u(m.y, iv);
        o.z = hmul2u(m.z, iv);
        o.w = hmul2u(m.w, iv);
        ((uint4*)(abf + (size_t)node * 128 + tile * 16))[u] = o;
    }
}

// --- K5: MFMA f16 GEMM in-place on d_out. A = abf [n][256] f16. ---
__global__ __launch_bounds__(256) void k_mfma_gemm(
    const unsigned short* __restrict__ abf,
    const unsigned short* __restrict__ Bp,
    const float* __restrict__ bias,
    float* __restrict__ out, int n_nodes)
{
    int wave = threadIdx.x >> 6;
    int lane = threadIdx.x & 63;
    int quad = lane >> 4;
    int l16  = lane & 15;
    int row0 = blockIdx.x * 64 + wave * 16;

    int arow = min(row0 + l16, n_nodes - 1);
    const unsigned short* arp = abf + (size_t)arow * 256 + quad * 8;
    half8 afrag[8];
    #pragma unroll
    for (int kb = 0; kb < 8; kb++)
        afrag[kb] = *((const half8*)(arp + kb * 32));

    f32x4 acc[8];
    #pragma unroll
    for (int f = 0; f < 8; f++) acc[f] = (f32x4){0.f, 0.f, 0.f, 0.f};

    #pragma unroll
    for (int kb = 0; kb < 8; kb++) {
        #pragma unroll
        for (int f = 0; f < 8; f++) {
            int n = f * 16 + l16;
            half8 bfrag = *((const half8*)(Bp + (((size_t)kb * 128 + n) * 4 + quad) * 8));
            acc[f] = __builtin_amdgcn_mfma_f32_16x16x32_f16(afrag[kb], bfrag, acc[f], 0, 0, 0);
        }
    }

    #pragma unroll
    for (int f = 0; f < 8; f++) {
        float bv = bias[f * 16 + l16];
        #pragma unroll
        for (int r = 0; r < 4; r++) {
            int row = row0 + quad * 4 + r;
            if (row < n_nodes)
                out[(size_t)row * DIM + f * 16 + l16] = acc[f][r] + bv;
        }
    }
}

extern "C" void kernel_launch(void* const* d_in, const int* in_sizes, int n_in,
                              void* d_out, int out_size, void* d_ws, size_t ws_size,
                              hipStream_t stream) {
    const float* x    = (const float*)d_in[0];
    const int*   edge = (const int*)  d_in[1];
    const float* Wn   = (const float*)d_in[2];
    const float* Ws   = (const float*)d_in[3];
    const float* b    = (const float*)d_in[4];
    float* out = (float*)d_out;

    const int n_nodes = in_sizes[0] / DIM;   // 50000
    const int n_edges = in_sizes[1] / 2;     // 1600000
    const int nb = (n_nodes + 127) >> 7;     // 391

    // ws: entries[nb*CAP] u32 | nbr[nb*CAP] u16 | offsets[N] u32 | degs[N] |
    //     bucket_cur[nb] | Bp (64KB).  xt (12.8MB) aliases entries after csort.
    unsigned* entries      = (unsigned*)d_ws;
    unsigned short* nbr    = (unsigned short*)(entries + (size_t)nb * CAP);
    unsigned* offsets      = (unsigned*)(nbr + (size_t)nb * CAP);
    int* degs              = (int*)(offsets + n_nodes);
    int* bucket_cur        = degs + n_nodes;
    unsigned short* Bp     = (unsigned short*)((((size_t)(bucket_cur + nb)) + 63) & ~(size_t)63);
    unsigned* xt           = entries;
    unsigned* abf          = (unsigned*)d_out;

    k_packw_init<<<128, 256, 0, stream>>>(Wn, Ws, Bp, bucket_cur, nb);

    const int bb = (n_edges + EPB - 1) / EPB;   // 782
    k_bin<<<bb, 256, 0, stream>>>(edge, bucket_cur, entries, n_edges, nb);
    k_csort<<<nb, 512, 0, stream>>>(entries, bucket_cur, offsets, degs, nbr, n_nodes);

    const int nconv = n_nodes * 16 * NTILES;
    k_tof16t<<<(nconv + 255) / 256, 256, 0, stream>>>(x, xt, abf, n_nodes);

    dim3 ggrid((n_nodes + 63) / 64, NTILES);
    k_gather<<<ggrid, 256, 0, stream>>>(xt, offsets, degs, nbr, abf, n_nodes);

    const int mb = (n_nodes + 63) / 64;
    k_mfma_gemm<<<mb, 256, 0, stream>>>((const unsigned short*)abf, Bp, b,
                                        out, n_nodes);
}

// Round 5
// 269.041 us; speedup vs baseline: 1.1512x; 1.1512x over previous
//
#include <hip/hip_runtime.h>
#include <hip/hip_fp16.h>

// GNN mean-aggregate + dual GEMM. N=50000, E=1.6M, DIM=128, fp32 in/out.
// Pipeline: fixed-capacity bucket bin (block-local LDS counting sort +
// coalesced streaming writeback) -> per-bucket counting sort (8-way
// privatized) -> column-tiled register gather -> MFMA f16 GEMM in-place.
// R1: 4-deep pipeline (NEUTRAL - not latency-bound).
// R2: full-width 1-wave/node gather: VALU 48->21% but FETCH 75->284MB.
// R3: tile loop inside wave: FETCH 445MB (tiles concurrent) - REVERTED.
// R4: treeless gather (VALU 48->10%, good) but grid.y tiling broke:
//     782 blocks/tile < ~2048 resident -> all tiles concurrent, FETCH
//     438MB, L2-miss path saturated at ~3.5 TB/s.
// R5: serialize tile passes via 4 kernel LAUNCHES (in-stream kernels
//     fully serialize -> guaranteed 3.2MB L2 residency per pass,
//     independent of block count). 8 lanes/node (even/odd entry halves,
//     single shfl_xor(4) merge) doubles waves/pass to ~24/CU and halves
//     deg imbalance.

constexpr int DIM    = 128;
constexpr int NBMAX  = 512;    // coarse buckets (node>>7); N=50000 -> 391
constexpr int EPB    = 2048;   // edges per binning block (256 thr x 8)
constexpr int CAP    = 9216;   // entries per bucket (E[cnt]=8184, ~11 sigma)
constexpr int COLT   = 32;     // columns per tile -> 4 tiles
constexpr int NTILES = DIM / COLT;

typedef _Float16 half8 __attribute__((ext_vector_type(8)));
typedef __attribute__((ext_vector_type(4))) float f32x4;

__device__ __forceinline__ unsigned hadd2u(unsigned a, unsigned b) {
    __half2 ha = *reinterpret_cast<__half2*>(&a);
    __half2 hb = *reinterpret_cast<__half2*>(&b);
    __half2 r  = __hadd2(ha, hb);
    return *reinterpret_cast<unsigned*>(&r);
}
__device__ __forceinline__ unsigned hmul2u(unsigned a, __half2 s) {
    __half2 ha = *reinterpret_cast<__half2*>(&a);
    __half2 r  = __hmul2(ha, s);
    return *reinterpret_cast<unsigned*>(&r);
}
__device__ __forceinline__ unsigned packf16(float x, float y) {
    __half2 h = __floats2half2_rn(x, y);
    return *reinterpret_cast<unsigned*>(&h);
}
__device__ __forceinline__ uint4 hadd2q(uint4 a, uint4 b) {
    uint4 r;
    r.x = hadd2u(a.x, b.x);
    r.y = hadd2u(a.y, b.y);
    r.z = hadd2u(a.z, b.z);
    r.w = hadd2u(a.w, b.w);
    return r;
}

// --- K0: pack [Wn;Ws] -> Bp f16 (B-fragment order) AND init bucket cursors ---
__global__ __launch_bounds__(256) void k_packw_init(
    const float* __restrict__ Wn, const float* __restrict__ Ws,
    unsigned short* __restrict__ Bp, int* __restrict__ bucket_cur, int nb)
{
    int i = blockIdx.x * 256 + threadIdx.x;
    if (i < nb) bucket_cur[i] = i * CAP;
    if (i >= 8 * 128 * 4 * 8) return;
    int j    = i & 7;
    int quad = (i >> 3) & 3;
    int n    = (i >> 5) & 127;
    int kb   = i >> 12;
    int k = kb * 32 + quad * 8 + j;
    float v = (k < 128) ? Wn[k * 128 + n] : Ws[(k - 128) * 128 + n];
    __half h = __float2half_rn(v);
    Bp[i] = *reinterpret_cast<unsigned short*>(&h);
}

// --- K1: bin endpoints into fixed-cap buckets.
// Per-wave LDS histogram -> global frontier alloc (1 atomic-return per
// (block,bucket)) -> block-local LDS counting sort -> coalesced writeback. ---
__global__ __launch_bounds__(256) void k_bin(
    const int* __restrict__ edge, int* __restrict__ bucket_cur,
    unsigned* __restrict__ entries, int n_edges, int nb)
{
    __shared__ int lh[4][NBMAX];
    __shared__ int Lb[NBMAX];
    __shared__ int gb[NBMAX];
    __shared__ int sc[512];
    __shared__ unsigned sorted[2 * EPB];
    __shared__ int      gaddr[2 * EPB];

    int t = threadIdx.x;
    int w = t >> 6;
    for (int i = t; i < 4 * NBMAX; i += 256) ((int*)lh)[i] = 0;
    __syncthreads();

    int e0 = blockIdx.x * EPB;
    int2 ev[8];
    #pragma unroll
    for (int k = 0; k < 8; k++) {
        int idx = e0 + k * 256 + t;
        if (idx < n_edges) {
            ev[k] = ((const int2*)edge)[idx];
            atomicAdd(&lh[w][ev[k].x >> 7], 1);
            atomicAdd(&lh[w][ev[k].y >> 7], 1);
        } else {
            ev[k].x = -1;
        }
    }
    __syncthreads();

    for (int i = t; i < 512; i += 256)
        sc[i] = (i < nb) ? (lh[0][i] + lh[1][i] + lh[2][i] + lh[3][i]) : 0;
    __syncthreads();
    for (int d = 1; d < 512; d <<= 1) {
        int v0 = 0, v1 = 0;
        int i0 = t, i1 = t + 256;
        if (i0 >= d) v0 = sc[i0 - d];
        if (i1 >= d) v1 = sc[i1 - d];
        __syncthreads();
        if (i0 >= d) sc[i0] += v0;
        if (i1 >= d) sc[i1] += v1;
        __syncthreads();
    }
    for (int i = t; i < nb; i += 256) {
        int c0 = lh[0][i], c1 = lh[1][i], c2 = lh[2][i], c3 = lh[3][i];
        int tot = c0 + c1 + c2 + c3;
        int L = sc[i] - tot;
        Lb[i] = L;
        gb[i] = tot ? atomicAdd(&bucket_cur[i], tot) : 0;
        lh[0][i] = L;
        lh[1][i] = L + c0;
        lh[2][i] = L + c0 + c1;
        lh[3][i] = L + c0 + c1 + c2;
    }
    __syncthreads();

    #pragma unroll
    for (int k = 0; k < 8; k++) {
        int a = ev[k].x;
        if (a < 0) continue;
        int b = ev[k].y;
        int ba = a >> 7, bb = b >> 7;
        int sa = atomicAdd(&lh[w][ba], 1);
        sorted[sa] = ((unsigned)(a & 127) << 16) | (unsigned)b;
        gaddr[sa]  = gb[ba] + sa - Lb[ba];
        int sb = atomicAdd(&lh[w][bb], 1);
        sorted[sb] = ((unsigned)(b & 127) << 16) | (unsigned)a;
        gaddr[sb]  = gb[bb] + sb - Lb[bb];
    }
    __syncthreads();

    int cntb = sc[511];
    for (int p = t; p < cntb; p += 256)
        entries[gaddr[p]] = sorted[p];
}

// --- K2: per-bucket counting sort, 512 threads, 8-way privatized cursors ---
__global__ __launch_bounds__(512) void k_csort(
    const unsigned* __restrict__ entries, const int* __restrict__ bucket_cur,
    unsigned* __restrict__ offsets, int* __restrict__ degs,
    unsigned short* __restrict__ nbr, int n_nodes)
{
    int b    = blockIdx.x;
    int base = b * CAP;
    int cnt  = bucket_cur[b] - base;
    __shared__ int lh[8][128];
    __shared__ int scn[128];
    int t = threadIdx.x;
    int w = t >> 6;
    for (int i = t; i < 8 * 128; i += 512) ((int*)lh)[i] = 0;
    __syncthreads();
    for (int i = t; i < cnt; i += 512)
        atomicAdd(&lh[w][entries[base + i] >> 16], 1);
    __syncthreads();
    int tot = 0;
    if (t < 128) {
        #pragma unroll
        for (int ww = 0; ww < 8; ww++) tot += lh[ww][t];
        scn[t] = tot;
    }
    __syncthreads();
    for (int d = 1; d < 128; d <<= 1) {
        int u = (t >= d && t < 128) ? scn[t - d] : 0;
        __syncthreads();
        if (t >= d && t < 128) scn[t] += u;
        __syncthreads();
    }
    if (t < 128) {
        int excl = scn[t] - tot;
        int node = (b << 7) + t;
        if (node < n_nodes) {
            offsets[node] = (unsigned)(base + excl);
            degs[node]    = tot;
        }
        int run = excl;
        #pragma unroll
        for (int ww = 0; ww < 8; ww++) { int c = lh[ww][t]; lh[ww][t] = run; run += c; }
    }
    __syncthreads();
    for (int i = t; i < cnt; i += 512) {
        unsigned e = entries[base + i];
        int slot = atomicAdd(&lh[w][e >> 16], 1);
        nbr[base + slot] = (unsigned short)(e & 0xFFFFu);
    }
}

// --- K3: x fp32 -> xt (4 f16 column tiles) AND x-half of f16 A (cols 128..255) ---
__global__ __launch_bounds__(256) void k_tof16t(
    const float* __restrict__ x, unsigned* __restrict__ xt,
    unsigned* __restrict__ abf, int n_nodes)
{
    int i = blockIdx.x * 256 + threadIdx.x;
    int per = n_nodes * 16;
    if (i >= per * NTILES) return;
    int t   = i / per;
    int rem = i - t * per;
    int n   = rem >> 4;
    int u   = rem & 15;
    float2 f = ((const float2*)(x + (size_t)n * DIM + t * COLT))[u];
    unsigned pk = packf16(f.x, f.y);
    xt[i] = pk;
    abf[(size_t)n * 128 + 64 + t * 16 + u] = pk;
}

// --- K4 (R5): treeless-ish tiled gather + mean, ONE TILE PER LAUNCH.
// 8 lanes/node: lane sub 0..7 = (half h = sub>>2, uint4 u = sub&3).
// Each 4-lane half streams the node's even/odd entries with 4 depth
// slots (8 rows in flight per node), then one shfl_xor(4) merge level.
// 8 nodes/wave -> 6250 waves/pass (~24/CU). Tile passes serialize at
// the kernel boundary -> 3.2MB xt tile stays L2-resident.
__global__ __launch_bounds__(256) void k_gather(
    const unsigned* __restrict__ xt,        // [NTILES][n_nodes][16] uints
    const unsigned* __restrict__ offsets,
    const int* __restrict__ degs,
    const unsigned short* __restrict__ nbr,
    unsigned* __restrict__ abf, int n_nodes, int tile)
{
    int wave = threadIdx.x >> 6;
    int lane = threadIdx.x & 63;
    int grp  = lane >> 3;          // 0..7: node within the wave
    int sub  = lane & 7;
    int h    = sub >> 2;           // entry-parity half
    int u    = sub & 3;            // uint4 within the 64B row-tile
    int node = blockIdx.x * 32 + wave * 8 + grp;
    const uint4* xt_tile = (const uint4*)(xt + (size_t)tile * n_nodes * 16);
    bool valid = node < n_nodes;
    int base = 0, deg = 0;
    if (valid) { base = (int)offsets[node]; deg = degs[node]; }
    int end = base + deg;

    uint4 s0 = {0u, 0u, 0u, 0u};
    uint4 s1 = s0, s2 = s0, s3 = s0;

    int i = base + h;
    for (; i + 6 < end; i += 8) {
        int v0 = nbr[i];
        int v1 = nbr[i + 2];
        int v2 = nbr[i + 4];
        int v3 = nbr[i + 6];
        uint4 w0 = xt_tile[v0 * 4 + u];
        uint4 w1 = xt_tile[v1 * 4 + u];
        uint4 w2 = xt_tile[v2 * 4 + u];
        uint4 w3 = xt_tile[v3 * 4 + u];
        s0 = hadd2q(s0, w0);
        s1 = hadd2q(s1, w1);
        s2 = hadd2q(s2, w2);
        s3 = hadd2q(s3, w3);
    }
    for (; i < end; i += 2) {
        int v = nbr[i];
        s0 = hadd2q(s0, xt_tile[v * 4 + u]);
    }

    uint4 m = hadd2q(hadd2q(s0, s1), hadd2q(s2, s3));

    // merge the two entry-parity halves (lane bit 2)
    uint4 mm;
    mm.x = (unsigned)__shfl_xor((int)m.x, 4);
    mm.y = (unsigned)__shfl_xor((int)m.y, 4);
    mm.z = (unsigned)__shfl_xor((int)m.z, 4);
    mm.w = (unsigned)__shfl_xor((int)m.w, 4);
    m = hadd2q(m, mm);

    if (valid && h == 0) {
        float inv = 1.0f / fmaxf((float)deg, 1.0f);
        __half2 iv = __float2half2_rn(inv);
        uint4 o;
        o.x = hmul2u(m.x, iv);
        o.y = hmul2u(m.y, iv);
        o.z = hmul2u(m.z, iv);
        o.w = hmul2u(m.w, iv);
        ((uint4*)(abf + (size_t)node * 128 + tile * 16))[u] = o;
    }
}

// --- K5: MFMA f16 GEMM in-place on d_out. A = abf [n][256] f16. ---
__global__ __launch_bounds__(256) void k_mfma_gemm(
    const unsigned short* __restrict__ abf,
    const unsigned short* __restrict__ Bp,
    const float* __restrict__ bias,
    float* __restrict__ out, int n_nodes)
{
    int wave = threadIdx.x >> 6;
    int lane = threadIdx.x & 63;
    int quad = lane >> 4;
    int l16  = lane & 15;
    int row0 = blockIdx.x * 64 + wave * 16;

    int arow = min(row0 + l16, n_nodes - 1);
    const unsigned short* arp = abf + (size_t)arow * 256 + quad * 8;
    half8 afrag[8];
    #pragma unroll
    for (int kb = 0; kb < 8; kb++)
        afrag[kb] = *((const half8*)(arp + kb * 32));

    f32x4 acc[8];
    #pragma unroll
    for (int f = 0; f < 8; f++) acc[f] = (f32x4){0.f, 0.f, 0.f, 0.f};

    #pragma unroll
    for (int kb = 0; kb < 8; kb++) {
        #pragma unroll
        for (int f = 0; f < 8; f++) {
            int n = f * 16 + l16;
            half8 bfrag = *((const half8*)(Bp + (((size_t)kb * 128 + n) * 4 + quad) * 8));
            acc[f] = __builtin_amdgcn_mfma_f32_16x16x32_f16(afrag[kb], bfrag, acc[f], 0, 0, 0);
        }
    }

    #pragma unroll
    for (int f = 0; f < 8; f++) {
        float bv = bias[f * 16 + l16];
        #pragma unroll
        for (int r = 0; r < 4; r++) {
            int row = row0 + quad * 4 + r;
            if (row < n_nodes)
                out[(size_t)row * DIM + f * 16 + l16] = acc[f][r] + bv;
        }
    }
}

extern "C" void kernel_launch(void* const* d_in, const int* in_sizes, int n_in,
                              void* d_out, int out_size, void* d_ws, size_t ws_size,
                              hipStream_t stream) {
    const float* x    = (const float*)d_in[0];
    const int*   edge = (const int*)  d_in[1];
    const float* Wn   = (const float*)d_in[2];
    const float* Ws   = (const float*)d_in[3];
    const float* b    = (const float*)d_in[4];
    float* out = (float*)d_out;

    const int n_nodes = in_sizes[0] / DIM;   // 50000
    const int n_edges = in_sizes[1] / 2;     // 1600000
    const int nb = (n_nodes + 127) >> 7;     // 391

    // ws: entries[nb*CAP] u32 | nbr[nb*CAP] u16 | offsets[N] u32 | degs[N] |
    //     bucket_cur[nb] | Bp (64KB).  xt (12.8MB) aliases entries after csort.
    unsigned* entries      = (unsigned*)d_ws;
    unsigned short* nbr    = (unsigned short*)(entries + (size_t)nb * CAP);
    unsigned* offsets      = (unsigned*)(nbr + (size_t)nb * CAP);
    int* degs              = (int*)(offsets + n_nodes);
    int* bucket_cur        = degs + n_nodes;
    unsigned short* Bp     = (unsigned short*)((((size_t)(bucket_cur + nb)) + 63) & ~(size_t)63);
    unsigned* xt           = entries;
    unsigned* abf          = (unsigned*)d_out;

    k_packw_init<<<128, 256, 0, stream>>>(Wn, Ws, Bp, bucket_cur, nb);

    const int bb = (n_edges + EPB - 1) / EPB;   // 782
    k_bin<<<bb, 256, 0, stream>>>(edge, bucket_cur, entries, n_edges, nb);
    k_csort<<<nb, 512, 0, stream>>>(entries, bucket_cur, offsets, degs, nbr, n_nodes);

    const int nconv = n_nodes * 16 * NTILES;
    k_tof16t<<<(nconv + 255) / 256, 256, 0, stream>>>(x, xt, abf, n_nodes);

    const int gblocks = (n_nodes + 31) / 32;    // 1563
    for (int tile = 0; tile < NTILES; tile++)
        k_gather<<<gblocks, 256, 0, stream>>>(xt, offsets, degs, nbr, abf,
                                              n_nodes, tile);

    const int mb = (n_nodes + 63) / 64;
    k_mfma_gemm<<<mb, 256, 0, stream>>>((const unsigned short*)abf, Bp, b,
                                        out, n_nodes);
}

// Round 6
// 250.175 us; speedup vs baseline: 1.2381x; 1.0754x over previous
//
#include <hip/hip_runtime.h>
#include <hip/hip_fp16.h>

// GNN mean-aggregate + dual GEMM. N=50000, E=1.6M, DIM=128, fp32 in/out.
// Pipeline (5 launches): k_prep (pack W + init cursors + x->f16 x-half of A)
// -> k_bin (bucket bin) -> k_csort (per-bucket counting sort -> u16 CSR)
// -> k_gather (full-width register gather from A's x-half) -> MFMA GEMM.
// R1: 4-deep pipeline (NEUTRAL - not latency-bound).
// R2: full-width 1-wave/node gather: 83us, FETCH 284MB but NOT slower ->
// R3/R4: tile-footprint chasing: FETCH down never helped, time worse.
// R5: serialized tile passes: per-pass <42us but total +17 (launch gaps).
// SYNTHESIS: gather is bound at ~150G 64B-granule requests/s in EVERY
// regime (R0 L2-hit 88us, R2 HBM-miss 83us, R5 serialized ~86us, all
// 12.8M granules). 3.2M entries x 256B = 12.8M granules = ~83us floor.
// FETCH_SIZE is free here; footprint engineering was chasing the wrong
// counter. Launch gaps ~6us each.
// R6: gather = R2 version (request floor, 1 launch, no xt tensor);
// fuse packw+init+tof16t into k_prep. 9 -> 5 launches.

constexpr int DIM    = 128;
constexpr int NBMAX  = 512;    // coarse buckets (node>>7); N=50000 -> 391
constexpr int EPB    = 2048;   // edges per binning block (256 thr x 8)
constexpr int CAP    = 9216;   // entries per bucket (E[cnt]=8184, ~11 sigma)

typedef _Float16 half8 __attribute__((ext_vector_type(8)));
typedef __attribute__((ext_vector_type(4))) float f32x4;

__device__ __forceinline__ unsigned hadd2u(unsigned a, unsigned b) {
    __half2 ha = *reinterpret_cast<__half2*>(&a);
    __half2 hb = *reinterpret_cast<__half2*>(&b);
    __half2 r  = __hadd2(ha, hb);
    return *reinterpret_cast<unsigned*>(&r);
}
__device__ __forceinline__ unsigned hmul2u(unsigned a, __half2 s) {
    __half2 ha = *reinterpret_cast<__half2*>(&a);
    __half2 r  = __hmul2(ha, s);
    return *reinterpret_cast<unsigned*>(&r);
}
__device__ __forceinline__ unsigned packf16(float x, float y) {
    __half2 h = __floats2half2_rn(x, y);
    return *reinterpret_cast<unsigned*>(&h);
}

// --- K0 (R6): fused prep. Three independent jobs, all pre-bin/pre-gather:
// (a) bucket_cur[i] = i*CAP; (b) pack [Wn;Ws] -> Bp f16 B-fragments;
// (c) x fp32 -> f16 x-half of A (abf cols 128..255). ---
__global__ __launch_bounds__(256) void k_prep(
    const float* __restrict__ Wn, const float* __restrict__ Ws,
    const float* __restrict__ x,
    unsigned short* __restrict__ Bp, int* __restrict__ bucket_cur,
    unsigned* __restrict__ abf, int nb, int n_nodes)
{
    int i = blockIdx.x * 256 + threadIdx.x;
    if (i < nb) bucket_cur[i] = i * CAP;
    if (i < 8 * 128 * 4 * 8) {
        int j    = i & 7;
        int quad = (i >> 3) & 3;
        int n    = (i >> 5) & 127;
        int kb   = i >> 12;
        int k = kb * 32 + quad * 8 + j;
        float v = (k < 128) ? Wn[k * 128 + n] : Ws[(k - 128) * 128 + n];
        __half h = __float2half_rn(v);
        Bp[i] = *reinterpret_cast<unsigned short*>(&h);
    }
    if (i < n_nodes * 64) {
        int n = i >> 6;
        int u = i & 63;
        float2 f = ((const float2*)(x + (size_t)n * DIM))[u];
        abf[(size_t)n * 128 + 64 + u] = packf16(f.x, f.y);
    }
}

// --- K1: bin endpoints into fixed-cap buckets.
// Per-wave LDS histogram -> global frontier alloc (1 atomic-return per
// (block,bucket)) -> block-local LDS counting sort -> coalesced writeback. ---
__global__ __launch_bounds__(256) void k_bin(
    const int* __restrict__ edge, int* __restrict__ bucket_cur,
    unsigned* __restrict__ entries, int n_edges, int nb)
{
    __shared__ int lh[4][NBMAX];
    __shared__ int Lb[NBMAX];
    __shared__ int gb[NBMAX];
    __shared__ int sc[512];
    __shared__ unsigned sorted[2 * EPB];
    __shared__ int      gaddr[2 * EPB];

    int t = threadIdx.x;
    int w = t >> 6;
    for (int i = t; i < 4 * NBMAX; i += 256) ((int*)lh)[i] = 0;
    __syncthreads();

    int e0 = blockIdx.x * EPB;
    int2 ev[8];
    #pragma unroll
    for (int k = 0; k < 8; k++) {
        int idx = e0 + k * 256 + t;
        if (idx < n_edges) {
            ev[k] = ((const int2*)edge)[idx];
            atomicAdd(&lh[w][ev[k].x >> 7], 1);
            atomicAdd(&lh[w][ev[k].y >> 7], 1);
        } else {
            ev[k].x = -1;
        }
    }
    __syncthreads();

    for (int i = t; i < 512; i += 256)
        sc[i] = (i < nb) ? (lh[0][i] + lh[1][i] + lh[2][i] + lh[3][i]) : 0;
    __syncthreads();
    for (int d = 1; d < 512; d <<= 1) {
        int v0 = 0, v1 = 0;
        int i0 = t, i1 = t + 256;
        if (i0 >= d) v0 = sc[i0 - d];
        if (i1 >= d) v1 = sc[i1 - d];
        __syncthreads();
        if (i0 >= d) sc[i0] += v0;
        if (i1 >= d) sc[i1] += v1;
        __syncthreads();
    }
    for (int i = t; i < nb; i += 256) {
        int c0 = lh[0][i], c1 = lh[1][i], c2 = lh[2][i], c3 = lh[3][i];
        int tot = c0 + c1 + c2 + c3;
        int L = sc[i] - tot;
        Lb[i] = L;
        gb[i] = tot ? atomicAdd(&bucket_cur[i], tot) : 0;
        lh[0][i] = L;
        lh[1][i] = L + c0;
        lh[2][i] = L + c0 + c1;
        lh[3][i] = L + c0 + c1 + c2;
    }
    __syncthreads();

    #pragma unroll
    for (int k = 0; k < 8; k++) {
        int a = ev[k].x;
        if (a < 0) continue;
        int b = ev[k].y;
        int ba = a >> 7, bb = b >> 7;
        int sa = atomicAdd(&lh[w][ba], 1);
        sorted[sa] = ((unsigned)(a & 127) << 16) | (unsigned)b;
        gaddr[sa]  = gb[ba] + sa - Lb[ba];
        int sb = atomicAdd(&lh[w][bb], 1);
        sorted[sb] = ((unsigned)(b & 127) << 16) | (unsigned)a;
        gaddr[sb]  = gb[bb] + sb - Lb[bb];
    }
    __syncthreads();

    int cntb = sc[511];
    for (int p = t; p < cntb; p += 256)
        entries[gaddr[p]] = sorted[p];
}

// --- K2: per-bucket counting sort, 512 threads, 8-way privatized cursors ---
__global__ __launch_bounds__(512) void k_csort(
    const unsigned* __restrict__ entries, const int* __restrict__ bucket_cur,
    unsigned* __restrict__ offsets, int* __restrict__ degs,
    unsigned short* __restrict__ nbr, int n_nodes)
{
    int b    = blockIdx.x;
    int base = b * CAP;
    int cnt  = bucket_cur[b] - base;
    __shared__ int lh[8][128];
    __shared__ int scn[128];
    int t = threadIdx.x;
    int w = t >> 6;
    for (int i = t; i < 8 * 128; i += 512) ((int*)lh)[i] = 0;
    __syncthreads();
    for (int i = t; i < cnt; i += 512)
        atomicAdd(&lh[w][entries[base + i] >> 16], 1);
    __syncthreads();
    int tot = 0;
    if (t < 128) {
        #pragma unroll
        for (int ww = 0; ww < 8; ww++) tot += lh[ww][t];
        scn[t] = tot;
    }
    __syncthreads();
    for (int d = 1; d < 128; d <<= 1) {
        int u = (t >= d && t < 128) ? scn[t - d] : 0;
        __syncthreads();
        if (t >= d && t < 128) scn[t] += u;
        __syncthreads();
    }
    if (t < 128) {
        int excl = scn[t] - tot;
        int node = (b << 7) + t;
        if (node < n_nodes) {
            offsets[node] = (unsigned)(base + excl);
            degs[node]    = tot;
        }
        int run = excl;
        #pragma unroll
        for (int ww = 0; ww < 8; ww++) { int c = lh[ww][t]; lh[ww][t] = run; run += c; }
    }
    __syncthreads();
    for (int i = t; i < cnt; i += 512) {
        unsigned e = entries[base + i];
        int slot = atomicAdd(&lh[w][e >> 16], 1);
        nbr[base + slot] = (unsigned short)(e & 0xFFFFu);
    }
}

// --- K4 (= R2's proven kernel): full-width gather + mean. 1 wave/node,
// 4 entry groups x 16 lanes x 16B = 256B coalesced f16 row per entry,
// read straight from the x-half of abf. 4 depth-slot accumulators. ---
__global__ __launch_bounds__(256) void k_gather(
    const unsigned* __restrict__ offsets,
    const int* __restrict__ degs,
    const unsigned short* __restrict__ nbr,
    unsigned* __restrict__ abf, int n_nodes)
{
    int node = blockIdx.x * 4 + (threadIdx.x >> 6);
    if (node >= n_nodes) return;
    int lane = threadIdx.x & 63;
    int grp  = lane >> 4;          // 0..3: entry slot within iteration
    int u    = lane & 15;          // uint4 within the 256B row
    const uint4* xr = (const uint4*)abf;   // row v x-half: xr[v*32 + 16 + u]
    int base = (int)offsets[node];
    int deg  = degs[node];
    int end  = base + deg;

    // p{c}[d]: accumulator for uint4-component c, depth-slot d
    unsigned p0[4], p1[4], p2[4], p3[4];
    #pragma unroll
    for (int d = 0; d < 4; d++) { p0[d] = 0u; p1[d] = 0u; p2[d] = 0u; p3[d] = 0u; }

    int i = base + grp;
    for (; i + 12 < end; i += 16) {
        int v0 = nbr[i];
        int v1 = nbr[i + 4];
        int v2 = nbr[i + 8];
        int v3 = nbr[i + 12];
        uint4 w0 = xr[v0 * 32 + 16 + u];
        uint4 w1 = xr[v1 * 32 + 16 + u];
        uint4 w2 = xr[v2 * 32 + 16 + u];
        uint4 w3 = xr[v3 * 32 + 16 + u];
        p0[0] = hadd2u(p0[0], w0.x); p1[0] = hadd2u(p1[0], w0.y);
        p2[0] = hadd2u(p2[0], w0.z); p3[0] = hadd2u(p3[0], w0.w);
        p0[1] = hadd2u(p0[1], w1.x); p1[1] = hadd2u(p1[1], w1.y);
        p2[1] = hadd2u(p2[1], w1.z); p3[1] = hadd2u(p3[1], w1.w);
        p0[2] = hadd2u(p0[2], w2.x); p1[2] = hadd2u(p1[2], w2.y);
        p2[2] = hadd2u(p2[2], w2.z); p3[2] = hadd2u(p3[2], w2.w);
        p0[3] = hadd2u(p0[3], w3.x); p1[3] = hadd2u(p1[3], w3.y);
        p2[3] = hadd2u(p2[3], w3.z); p3[3] = hadd2u(p3[3], w3.w);
    }
    for (; i < end; i += 4) {
        int v0 = nbr[i];
        uint4 w0 = xr[v0 * 32 + 16 + u];
        p0[0] = hadd2u(p0[0], w0.x); p1[0] = hadd2u(p1[0], w0.y);
        p2[0] = hadd2u(p2[0], w0.z); p3[0] = hadd2u(p3[0], w0.w);
    }

    // merge depth slots (2-level tree)
    unsigned s0 = hadd2u(hadd2u(p0[0], p0[1]), hadd2u(p0[2], p0[3]));
    unsigned s1 = hadd2u(hadd2u(p1[0], p1[1]), hadd2u(p1[2], p1[3]));
    unsigned s2 = hadd2u(hadd2u(p2[0], p2[1]), hadd2u(p2[2], p2[3]));
    unsigned s3 = hadd2u(hadd2u(p3[0], p3[1]), hadd2u(p3[2], p3[3]));

    // reduce across 4 groups (lane bits 4,5)
    #pragma unroll
    for (int off = 16; off < 64; off <<= 1) {
        s0 = hadd2u(s0, (unsigned)__shfl_xor((int)s0, off));
        s1 = hadd2u(s1, (unsigned)__shfl_xor((int)s1, off));
        s2 = hadd2u(s2, (unsigned)__shfl_xor((int)s2, off));
        s3 = hadd2u(s3, (unsigned)__shfl_xor((int)s3, off));
    }

    if (grp == 0) {
        float inv = 1.0f / fmaxf((float)deg, 1.0f);
        __half2 iv = __float2half2_rn(inv);
        uint4 o;
        o.x = hmul2u(s0, iv);
        o.y = hmul2u(s1, iv);
        o.z = hmul2u(s2, iv);
        o.w = hmul2u(s3, iv);
        ((uint4*)(abf + (size_t)node * 128))[u] = o;
    }
}

// --- K5: MFMA f16 GEMM in-place on d_out. A = abf [n][256] f16. ---
__global__ __launch_bounds__(256) void k_mfma_gemm(
    const unsigned short* __restrict__ abf,
    const unsigned short* __restrict__ Bp,
    const float* __restrict__ bias,
    float* __restrict__ out, int n_nodes)
{
    int wave = threadIdx.x >> 6;
    int lane = threadIdx.x & 63;
    int quad = lane >> 4;
    int l16  = lane & 15;
    int row0 = blockIdx.x * 64 + wave * 16;

    int arow = min(row0 + l16, n_nodes - 1);
    const unsigned short* arp = abf + (size_t)arow * 256 + quad * 8;
    half8 afrag[8];
    #pragma unroll
    for (int kb = 0; kb < 8; kb++)
        afrag[kb] = *((const half8*)(arp + kb * 32));

    f32x4 acc[8];
    #pragma unroll
    for (int f = 0; f < 8; f++) acc[f] = (f32x4){0.f, 0.f, 0.f, 0.f};

    #pragma unroll
    for (int kb = 0; kb < 8; kb++) {
        #pragma unroll
        for (int f = 0; f < 8; f++) {
            int n = f * 16 + l16;
            half8 bfrag = *((const half8*)(Bp + (((size_t)kb * 128 + n) * 4 + quad) * 8));
            acc[f] = __builtin_amdgcn_mfma_f32_16x16x32_f16(afrag[kb], bfrag, acc[f], 0, 0, 0);
        }
    }

    #pragma unroll
    for (int f = 0; f < 8; f++) {
        float bv = bias[f * 16 + l16];
        #pragma unroll
        for (int r = 0; r < 4; r++) {
            int row = row0 + quad * 4 + r;
            if (row < n_nodes)
                out[(size_t)row * DIM + f * 16 + l16] = acc[f][r] + bv;
        }
    }
}

extern "C" void kernel_launch(void* const* d_in, const int* in_sizes, int n_in,
                              void* d_out, int out_size, void* d_ws, size_t ws_size,
                              hipStream_t stream) {
    const float* x    = (const float*)d_in[0];
    const int*   edge = (const int*)  d_in[1];
    const float* Wn   = (const float*)d_in[2];
    const float* Ws   = (const float*)d_in[3];
    const float* b    = (const float*)d_in[4];
    float* out = (float*)d_out;

    const int n_nodes = in_sizes[0] / DIM;   // 50000
    const int n_edges = in_sizes[1] / 2;     // 1600000
    const int nb = (n_nodes + 127) >> 7;     // 391

    // ws: entries[nb*CAP] u32 | nbr[nb*CAP] u16 | offsets[N] u32 | degs[N] |
    //     bucket_cur[nb] | Bp (64KB).
    unsigned* entries      = (unsigned*)d_ws;
    unsigned short* nbr    = (unsigned short*)(entries + (size_t)nb * CAP);
    unsigned* offsets      = (unsigned*)(nbr + (size_t)nb * CAP);
    int* degs              = (int*)(offsets + n_nodes);
    int* bucket_cur        = degs + n_nodes;
    unsigned short* Bp     = (unsigned short*)((((size_t)(bucket_cur + nb)) + 63) & ~(size_t)63);
    unsigned* abf          = (unsigned*)d_out;

    const int nprep = n_nodes * 64;          // 3.2M threads covers all 3 jobs
    k_prep<<<(nprep + 255) / 256, 256, 0, stream>>>(Wn, Ws, x, Bp, bucket_cur,
                                                    abf, nb, n_nodes);

    const int bb = (n_edges + EPB - 1) / EPB;   // 782
    k_bin<<<bb, 256, 0, stream>>>(edge, bucket_cur, entries, n_edges, nb);
    k_csort<<<nb, 512, 0, stream>>>(entries, bucket_cur, offsets, degs, nbr, n_nodes);

    k_gather<<<(n_nodes + 3) / 4, 256, 0, stream>>>(offsets, degs, nbr, abf, n_nodes);

    const int mb = (n_nodes + 63) / 64;
    k_mfma_gemm<<<mb, 256, 0, stream>>>((const unsigned short*)abf, Bp, b,
                                        out, n_nodes);
}